// Round 9
// baseline (146.318 us; speedup 1.0000x reference)
//
#include <hip/hip_runtime.h>
#include <math.h>

#define N_FILT   80
#define FILT_DIM 251
#define KPAD     256
#define SIG_LEN  32000
#define OUT_LEN  31750
#define BATCH    32
#define TPB      320       // 5 waves: wave w owns filter-block fb = w

#define STRIP    1024      // t-range per block
#define NREP     8         // shifted replicas -> every window is 16B aligned
#define LROW     644       // dwords per replica: %4==0 (16B align), /4 odd (bank spread)
#define OBS      80        // out-buffer row stride (dwords): %32==16 -> 2-way max

#define TWO_PI_F 6.28318530717958647692f

typedef __attribute__((ext_vector_type(8))) short    short8;   // raw 16B frag
typedef __attribute__((ext_vector_type(8))) _Float16 half8;    // fp16 A/B frag
typedef __attribute__((ext_vector_type(4))) float    float4v;  // C/D frag
typedef __attribute__((ext_vector_type(2))) float    float2v;  // nt-store pair

// ---------------------------------------------------------------------------
// Kernel 1: build 80 sinc band-pass filters directly in fp16.
// ---------------------------------------------------------------------------
__global__ __launch_bounds__(256) void build_filters_kernel(
    const float* __restrict__ b1, const float* __restrict__ band,
    unsigned short* __restrict__ fh)
{
    const int f = blockIdx.x;
    const int i = threadIdx.x;

    const float MINF = 50.0f / 16000.0f;
    const float fb = fabsf(b1[f]) + MINF;
    const float fe = fb + fabsf(band[f]) + MINF;

    float v = 0.0f;
    if (i < FILT_DIM) {
        int m = i - 125; m = (m < 0) ? -m : m;
        if (m == 0) v = 2.0f * fe - 2.0f * fb;
        else {
            float a1 = TWO_PI_F * fb * (float)m;
            float a2 = TWO_PI_F * fe * (float)m;
            v = 2.0f * fe * (sinf(a2) / a2) - 2.0f * fb * (sinf(a1) / a1);
        }
    }

    __shared__ float red[256];
    red[i] = (i < FILT_DIM) ? v : -INFINITY;
    __syncthreads();
    #pragma unroll
    for (int s = 128; s > 0; s >>= 1) {
        if (i < s) red[i] = fmaxf(red[i], red[i + s]);
        __syncthreads();
    }
    const float mx = red[0];

    const float w   = 0.54f - 0.46f * cosf(TWO_PI_F * (float)i / 250.0f);
    const float val = (i < FILT_DIM) ? (v / mx) * w : 0.0f;
    const _Float16 h = (_Float16)val;                 // RNE v_cvt_f16_f32
    fh[f * KPAD + i] = __builtin_bit_cast(unsigned short, h);  // pad rows = 0
}

// ---------------------------------------------------------------------------
// Kernel 2: conv as MFMA GEMM (fp16), wave-independent + Toeplitz register
// window + NONTEMPORAL stores.   C[f,t] = sum_k F[f,k] * x[t+k]
//   R8: output is write-once and exceeds L3 (325 MB > 256 MB); regular
//   stores write-allocate in L3 and HBM sees the (scrambled) eviction
//   stream -- the suspected cause of the persistent ~3.6 TB/s effective
//   write BW.  __builtin_nontemporal_store bypasses cache allocation so
//   HBM sees our actual 512B/instr, 2KB/row-event store order.
//   (R8b: nt-store requires clang ext_vector type, not HIP float2 class.)
//   Rest identical to R7 (Toeplitz 16-slot register window, 5 waves with
//   wave w owning filter-block w, one barrier, wave-private ob flush).
// ---------------------------------------------------------------------------
__global__ __launch_bounds__(TPB, 2) void sinc_mfma_kernel(
    const float* __restrict__ x,
    const unsigned short* __restrict__ fh,
    float* __restrict__ out)
{
    __shared__ __align__(16) unsigned xf[NREP * LROW];     // 20.6 KB
    __shared__ __align__(16) float    ob[5][16 * OBS];     // 25.6 KB

    const int tid = threadIdx.x;
    // XCD swizzle: raw%8 = XCD -> each XCD owns 128 contiguous (strip,n)
    // blocks = 4 complete batches.
    const unsigned raw = blockIdx.x;
    const unsigned swz = (raw & 7u) * 128u + (raw >> 3);
    const int strip = (int)(swz & 31u);
    const int n     = (int)(swz >> 5);
    const int e0    = strip * STRIP;
    const float* xp = x + (size_t)n * SIG_LEN;

    // ---- stage x: fp16, 8 shifted replicas (replica r, dword d = elems 2d+r,2d+r+1)
    for (int d = tid; d < LROW; d += TPB) {
        const int g = e0 + 2 * d;
        float v0, v1, v2;
        if (g + 2 < SIG_LEN) {
            float2 p = *(const float2*)(xp + g);
            v0 = p.x; v1 = p.y; v2 = xp[g + 2];
        } else {
            v0 = (g     < SIG_LEN) ? xp[g]     : 0.0f;
            v1 = (g + 1 < SIG_LEN) ? xp[g + 1] : 0.0f;
            v2 = (g + 2 < SIG_LEN) ? xp[g + 2] : 0.0f;
        }
        const _Float16 h0 = (_Float16)v0, h1 = (_Float16)v1, h2 = (_Float16)v2;
        union { _Float16 h[2]; unsigned u; } pe, po;
        pe.h[0] = h0; pe.h[1] = h1;          // elems 2d, 2d+1
        po.h[0] = h1; po.h[1] = h2;          // elems 2d+1, 2d+2
        xf[0 * LROW + d] = pe.u;                                  // r=0
        xf[1 * LROW + d] = po.u;                                  // r=1
        if (d >= 1) { xf[2 * LROW + d - 1] = pe.u;                // r=2
                      xf[3 * LROW + d - 1] = po.u; }              // r=3
        if (d >= 2) { xf[4 * LROW + d - 2] = pe.u;                // r=4
                      xf[5 * LROW + d - 2] = po.u; }              // r=5
        if (d >= 3) { xf[6 * LROW + d - 3] = pe.u;                // r=6
                      xf[7 * LROW + d - 3] = po.u; }              // r=7
    }

    // ---- A fragments: wave w reads its 16 filters (fb = w) ------------------
    const int lane = tid & 63;
    const int w    = tid >> 6;        // wave id == filter-block
    const int m    = lane & 15;       // B-col (t offset) / C-col
    const int q    = lane >> 4;       // quad: k = q*8+j ; C-row = q*4+reg
    short8 Ah[8];
    {
        const unsigned short* ph = fh + (w * 16 + m) * KPAD + q * 8;
        #pragma unroll
        for (int kb = 0; kb < 8; ++kb)
            Ah[kb] = *(const short8*)(ph + kb * 32);
    }
    __syncthreads();                  // the ONLY barrier

    // ---- main loop: 64 t-tiles, Toeplitz window, flush every 4 tiles -------
    // element start s = 16*tt + m + 8q + 32kb ; replica r = m&7
    // frag dword offset = base + 8*u, u = tt + 2*kb  (16B-aligned, balanced
    // 8 lanes per 16B bank group per b128 -> conflict-free)
    const int r = m & 7;
    const unsigned base = (unsigned)(r * LROW + 4 * (m >> 3) + 4 * q);

    float* const obw  = &ob[w][0];
    const int    c2   = 2 * (lane & 31);       // flush: group-local col pair
    const int    rh   = lane >> 5;             // flush: row parity
    const size_t row0 = ((size_t)n * N_FILT + w * 16) * OUT_LEN;

    uint4 Bw[16];                              // rolling window, slot = u & 15
    #pragma unroll
    for (int u = 0; u < 14; ++u)               // prefill u = 0..13
        Bw[u] = *(const uint4*)(&xf[base + 8u * u]);

    for (int gg = 0; gg < 4; ++gg) {           // 4 super-groups x 16 tiles
        #pragma unroll
        for (int g4 = 0; g4 < 4; ++g4) {       // 4 groups of 4 tiles (64 cols)
            #pragma unroll
            for (int tl = 0; tl < 4; ++tl) {
                const int tt = gg * 16 + g4 * 4 + tl;   // tile index
                // load u = tt+14 into slot (g4*4+tl+14)&15 (static)
                Bw[(g4 * 4 + tl + 14) & 15] =
                    *(const uint4*)(&xf[base + 8u * (unsigned)(tt + 14)]);

                float4v a0 = {0.f,0.f,0.f,0.f}, a1 = {0.f,0.f,0.f,0.f};
                #pragma unroll
                for (int kk = 0; kk < 4; ++kk) {   // kb = 2kk, 2kk+1
                    a0 = __builtin_amdgcn_mfma_f32_16x16x32_f16(
                             __builtin_bit_cast(half8, Ah[2*kk]),
                             __builtin_bit_cast(half8, Bw[(g4*4 + tl + 4*kk) & 15]),
                             a0, 0, 0, 0);
                    a1 = __builtin_amdgcn_mfma_f32_16x16x32_f16(
                             __builtin_bit_cast(half8, Ah[2*kk+1]),
                             __builtin_bit_cast(half8, Bw[(g4*4 + tl + 4*kk + 2) & 15]),
                             a1, 0, 0, 0);
                }
                const int oc = tl * 16 + m;        // group-local col
                #pragma unroll
                for (int rg = 0; rg < 4; ++rg)
                    obw[(q * 4 + rg) * OBS + oc] = a0[rg] + a1[rg];
            }

            // flush group: 8 nontemporal float2 stores (2 rows x 256 B each)
            const int t0 = e0 + (gg * 4 + g4) * 64 + c2;   // even
            if (t0 + 1 < OUT_LEN) {
                #pragma unroll
                for (int f = 0; f < 8; ++f) {
                    const int row = 2 * f + rh;
                    const float2v v = *(const float2v*)(&obw[row * OBS + c2]);
                    float2v* dst = (float2v*)(out + row0 + (size_t)row * OUT_LEN + t0);
                    __builtin_nontemporal_store(v, dst);
                }
            }
        }
    }
}

// ---------------------------------------------------------------------------
extern "C" void kernel_launch(void* const* d_in, const int* in_sizes, int n_in,
                              void* d_out, int out_size, void* d_ws, size_t ws_size,
                              hipStream_t stream)
{
    const float* x    = (const float*)d_in[0];
    const float* b1   = (const float*)d_in[1];
    const float* band = (const float*)d_in[2];
    float* outp = (float*)d_out;

    unsigned short* fh = (unsigned short*)d_ws;          // 80*256*2 B = 40 KB

    build_filters_kernel<<<dim3(N_FILT), dim3(256), 0, stream>>>(b1, band, fh);

    dim3 grid(32 * 32);                                  // (strip, n) swizzled
    sinc_mfma_kernel<<<grid, dim3(TPB), 0, stream>>>(x, fh, outp);
}

// Round 10
// 85.361 us; speedup vs baseline: 1.7141x; 1.7141x over previous
//
#include <hip/hip_runtime.h>
#include <math.h>

#define N_FILT   80
#define FILT_DIM 251
#define KPAD     256
#define SIG_LEN  32000
#define OUT_LEN  31750
#define BATCH    32
#define TPB      320       // 5 waves: wave w owns filter-block fb = w

#define STRIP    1024      // t-range per block
#define NREP     8         // shifted replicas -> every window is 16B aligned
#define LROW     644       // dwords per replica: %4==0 (16B align), /4 odd (bank spread)
#define OBS2     36        // ob row stride (dwords) for 32-col groups

#define TWO_PI_F 6.28318530717958647692f

typedef __attribute__((ext_vector_type(8))) short    short8;   // raw 16B frag
typedef __attribute__((ext_vector_type(8))) _Float16 half8;    // fp16 A/B frag
typedef __attribute__((ext_vector_type(4))) float    float4v;  // C/D frag
typedef __attribute__((ext_vector_type(2))) float    float2v;  // store pair

// ---------------------------------------------------------------------------
// Kernel 1: build 80 sinc band-pass filters directly in fp16.
// ---------------------------------------------------------------------------
__global__ __launch_bounds__(256) void build_filters_kernel(
    const float* __restrict__ b1, const float* __restrict__ band,
    unsigned short* __restrict__ fh)
{
    const int f = blockIdx.x;
    const int i = threadIdx.x;

    const float MINF = 50.0f / 16000.0f;
    const float fb = fabsf(b1[f]) + MINF;
    const float fe = fb + fabsf(band[f]) + MINF;

    float v = 0.0f;
    if (i < FILT_DIM) {
        int m = i - 125; m = (m < 0) ? -m : m;
        if (m == 0) v = 2.0f * fe - 2.0f * fb;
        else {
            float a1 = TWO_PI_F * fb * (float)m;
            float a2 = TWO_PI_F * fe * (float)m;
            v = 2.0f * fe * (sinf(a2) / a2) - 2.0f * fb * (sinf(a1) / a1);
        }
    }

    __shared__ float red[256];
    red[i] = (i < FILT_DIM) ? v : -INFINITY;
    __syncthreads();
    #pragma unroll
    for (int s = 128; s > 0; s >>= 1) {
        if (i < s) red[i] = fmaxf(red[i], red[i + s]);
        __syncthreads();
    }
    const float mx = red[0];

    const float w   = 0.54f - 0.46f * cosf(TWO_PI_F * (float)i / 250.0f);
    const float val = (i < FILT_DIM) ? (v / mx) * w : 0.0f;
    const _Float16 h = (_Float16)val;                 // RNE v_cvt_f16_f32
    fh[f * KPAD + i] = __builtin_bit_cast(unsigned short, h);  // pad rows = 0
}

// ---------------------------------------------------------------------------
// Kernel 2: conv as MFMA GEMM (fp16), occupancy-maximized.
//   C[f,t] = sum_k F[f,k] * x[t+k]
//   R10: probe the store-concurrency theory.  Reverted nt stores (R9: L3
//   helps).  Dropped Toeplitz reg window (R7: -1.9us, costs 64 VGPR) and
//   shrunk ob to 2-tile flush groups (25.6 -> 11.5 KB): total LDS 32.1 KB,
//   VGPR capped via __launch_bounds__(320,5) -> 4 blocks/CU = 20 waves/CU
//   (was 15), stores issued every 2 tiles -> ~33% more outstanding writes.
//   Rest as R6/R7: 5 waves, wave w owns fb=w; staging once; ONE barrier;
//   wave-private ob gather + conflict-free float2 flush; no vmcnt drains.
// ---------------------------------------------------------------------------
__global__ __launch_bounds__(TPB, 5) void sinc_mfma_kernel(
    const float* __restrict__ x,
    const unsigned short* __restrict__ fh,
    float* __restrict__ out)
{
    __shared__ __align__(16) unsigned xf[NREP * LROW];     // 20.6 KB
    __shared__ __align__(16) float    ob[5][16 * OBS2];    // 11.5 KB

    const int tid = threadIdx.x;
    // XCD swizzle: raw%8 = XCD -> each XCD owns 128 contiguous (strip,n)
    // blocks = 4 complete batches.
    const unsigned raw = blockIdx.x;
    const unsigned swz = (raw & 7u) * 128u + (raw >> 3);
    const int strip = (int)(swz & 31u);
    const int n     = (int)(swz >> 5);
    const int e0    = strip * STRIP;
    const float* xp = x + (size_t)n * SIG_LEN;

    // ---- stage x: fp16, 8 shifted replicas (replica r, dword d = elems 2d+r,2d+r+1)
    for (int d = tid; d < LROW; d += TPB) {
        const int g = e0 + 2 * d;
        float v0, v1, v2;
        if (g + 2 < SIG_LEN) {
            float2 p = *(const float2*)(xp + g);
            v0 = p.x; v1 = p.y; v2 = xp[g + 2];
        } else {
            v0 = (g     < SIG_LEN) ? xp[g]     : 0.0f;
            v1 = (g + 1 < SIG_LEN) ? xp[g + 1] : 0.0f;
            v2 = (g + 2 < SIG_LEN) ? xp[g + 2] : 0.0f;
        }
        const _Float16 h0 = (_Float16)v0, h1 = (_Float16)v1, h2 = (_Float16)v2;
        union { _Float16 h[2]; unsigned u; } pe, po;
        pe.h[0] = h0; pe.h[1] = h1;          // elems 2d, 2d+1
        po.h[0] = h1; po.h[1] = h2;          // elems 2d+1, 2d+2
        xf[0 * LROW + d] = pe.u;                                  // r=0
        xf[1 * LROW + d] = po.u;                                  // r=1
        if (d >= 1) { xf[2 * LROW + d - 1] = pe.u;                // r=2
                      xf[3 * LROW + d - 1] = po.u; }              // r=3
        if (d >= 2) { xf[4 * LROW + d - 2] = pe.u;                // r=4
                      xf[5 * LROW + d - 2] = po.u; }              // r=5
        if (d >= 3) { xf[6 * LROW + d - 3] = pe.u;                // r=6
                      xf[7 * LROW + d - 3] = po.u; }              // r=7
    }

    // ---- A fragments: wave w reads its 16 filters (fb = w) ------------------
    const int lane = tid & 63;
    const int w    = tid >> 6;        // wave id == filter-block
    const int m    = lane & 15;       // B-col (t offset) / C-col
    const int q    = lane >> 4;       // quad: k = q*8+j ; C-row = q*4+reg
    short8 Ah[8];
    {
        const unsigned short* ph = fh + (w * 16 + m) * KPAD + q * 8;
        #pragma unroll
        for (int kb = 0; kb < 8; ++kb)
            Ah[kb] = *(const short8*)(ph + kb * 32);
    }
    __syncthreads();                  // the ONLY barrier

    // ---- main loop: 64 t-tiles in 32 groups of 2, flush per group ----------
    // element start s = 16*tt + m + 8q + 32kb ; replica r = m&7
    // frag dword offset = base + 8*tt + 16*kb  (16B-aligned, balanced
    // 8 lanes per 16B bank group per b128 -> conflict-free)
    const int r = m & 7;
    const unsigned base = (unsigned)(r * LROW + 4 * (m >> 3) + 4 * q);

    float* const obw  = &ob[w][0];
    const int    cp   = 2 * (lane & 15);       // flush: group-local col pair
    const int    rr0  = lane >> 4;             // flush: row 0..3 (+4j)
    const size_t row0 = ((size_t)n * N_FILT + w * 16) * OUT_LEN;

    for (int gp = 0; gp < 32; ++gp) {          // 32 groups of 32 cols
        #pragma unroll
        for (int tl = 0; tl < 2; ++tl) {
            const int tt = gp * 2 + tl;
            float4v a0 = {0.f,0.f,0.f,0.f}, a1 = {0.f,0.f,0.f,0.f};
            const unsigned o0 = base + 8u * (unsigned)tt;
            #pragma unroll
            for (int kk = 0; kk < 4; ++kk) {   // kb = 2kk (a0), 2kk+1 (a1)
                a0 = __builtin_amdgcn_mfma_f32_16x16x32_f16(
                         __builtin_bit_cast(half8, Ah[2*kk]),
                         __builtin_bit_cast(half8, *(const uint4*)(&xf[o0 + 32*kk])),
                         a0, 0, 0, 0);
                a1 = __builtin_amdgcn_mfma_f32_16x16x32_f16(
                         __builtin_bit_cast(half8, Ah[2*kk+1]),
                         __builtin_bit_cast(half8, *(const uint4*)(&xf[o0 + 32*kk + 16])),
                         a1, 0, 0, 0);
            }
            const int oc = tl * 16 + m;        // group-local col
            #pragma unroll
            for (int rg = 0; rg < 4; ++rg)
                obw[(q * 4 + rg) * OBS2 + oc] = a0[rg] + a1[rg];
        }

        // flush group: 4 float2 stores (4 rows x 128 B each), conflict-free
        const int t0 = e0 + gp * 32 + cp;      // even; OUT_LEN even
        if (t0 + 1 < OUT_LEN) {
            #pragma unroll
            for (int j = 0; j < 4; ++j) {
                const int row = j * 4 + rr0;
                const float2v v = *(const float2v*)(&obw[row * OBS2 + cp]);
                *(float2v*)(out + row0 + (size_t)row * OUT_LEN + t0) = v;
            }
        }
    }
}

// ---------------------------------------------------------------------------
extern "C" void kernel_launch(void* const* d_in, const int* in_sizes, int n_in,
                              void* d_out, int out_size, void* d_ws, size_t ws_size,
                              hipStream_t stream)
{
    const float* x    = (const float*)d_in[0];
    const float* b1   = (const float*)d_in[1];
    const float* band = (const float*)d_in[2];
    float* outp = (float*)d_out;

    unsigned short* fh = (unsigned short*)d_ws;          // 80*256*2 B = 40 KB

    build_filters_kernel<<<dim3(N_FILT), dim3(256), 0, stream>>>(b1, band, fh);

    dim3 grid(32 * 32);                                  // (strip, n) swizzled
    sinc_mfma_kernel<<<grid, dim3(TPB), 0, stream>>>(x, fh, outp);
}